// Round 1
// baseline (141.619 us; speedup 1.0000x reference)
//
#include <hip/hip_runtime.h>
#include <hip/hip_bf16.h>

#define C 128
#define H 256
#define W 256
#define HW (H * W)
#define CHW (C * H * W)
#define NTAB 16

// PyTorch bicubic kernel, a = -0.75
__device__ __forceinline__ float cubic075(float u) {
    float au = fabsf(u);
    float near_ = (1.25f * au - 2.25f) * au * au + 1.0f;
    float far_  = -0.75f * (((au - 5.0f) * au + 8.0f) * au - 4.0f);
    return au <= 1.0f ? near_ : (au < 2.0f ? far_ : 0.0f);
}

// Weights for output index o of _bicubic_weight_matrix(768, 4)[128:384]
__device__ __forceinline__ void bicubic_w4(int o, float* w4) {
    const float scale = 4.0f / 768.0f;
    float src = ((float)(o + 128) + 0.5f) * scale - 0.5f;
    float i0f = floorf(src);
    float t = src - i0f;
    int i0 = (int)i0f;
    w4[0] = w4[1] = w4[2] = w4[3] = 0.0f;
#pragma unroll
    for (int j = 0; j < 4; ++j) {
        int off = j - 1;
        float wv = cubic075(t - (float)off);
        int idx = i0 + off;
        idx = idx < 0 ? 0 : (idx > 3 ? 3 : idx);
        w4[idx] += wv;
    }
}

// ---------------- Stage 1: per-channel sum / sumsq over pre_x ----------------
// grid = C*8 blocks of 256 threads; each block reduces 8192 elements of one
// channel and atomicAdds its partial into ws[0:C) (sum) / ws[C:2C) (sumsq).
__global__ __launch_bounds__(256) void stats_kernel(const float* __restrict__ x,
                                                    float* __restrict__ ws) {
    int c = blockIdx.x >> 3;
    int seg = blockIdx.x & 7;
    const float4* x4 = (const float4*)(x + CHW) + (size_t)c * (HW / 4) + seg * 2048;
    float s = 0.0f, s2 = 0.0f;
#pragma unroll
    for (int k = 0; k < 8; ++k) {
        float4 v = x4[k * 256 + threadIdx.x];
        s  += v.x + v.y + v.z + v.w;
        s2 += v.x * v.x + v.y * v.y + v.z * v.z + v.w * v.w;
    }
#pragma unroll
    for (int off = 32; off > 0; off >>= 1) {
        s  += __shfl_down(s, off);
        s2 += __shfl_down(s2, off);
    }
    __shared__ float sd[8];
    int wid = threadIdx.x >> 6;
    if ((threadIdx.x & 63) == 0) { sd[wid] = s; sd[4 + wid] = s2; }
    __syncthreads();
    if (threadIdx.x == 0) {
        float ts  = sd[0] + sd[1] + sd[2] + sd[3];
        float ts2 = sd[4] + sd[5] + sd[6] + sd[7];
        atomicAdd(&ws[c], ts);
        atomicAdd(&ws[C + c], ts2);
    }
}

// ---------------- Stage 2: finalize stats, build 4x4 patches ----------------
// ws layout (floats):
//   [0,C)      sum        [C,2C)     sumsq
//   [2C,3C)    scaleP     [3C,4C)    biasP        (pre-half affine)
//   [4C,20C)   meanPatch[16][C]
//   [20C,36C)  invPatch[16][C]
__global__ __launch_bounds__(128) void finalize_kernel(
    const float* __restrict__ mean_table, const float* __restrict__ std_table,
    const float* __restrict__ weight, const float* __restrict__ bias,
    const int* __restrict__ yA, const int* __restrict__ xA,
    const int* __restrict__ pyA, const int* __restrict__ pxA,
    float* __restrict__ ws) {
    int c = threadIdx.x;
    const float n = (float)HW;
    float sum = ws[c], sumsq = ws[C + c];
    float mean = sum / n;
    float var = (sumsq - sum * sum / n) / (n - 1.0f);
    float stdv = sqrtf(var);
    float wgt = weight[c], bs = bias[c];
    float sp = wgt / stdv;
    ws[2 * C + c] = sp;
    ws[3 * C + c] = bs - mean * sp;

    int ya = *yA, xa = *xA, py = *pyA, px = *pxA;
    // dynamic_slice start clamp on the (19,19) padded table
    ya = min(max(ya, 0), 19 - 4);
    xa = min(max(xa, 0), 19 - 4);
    float* meanPatch = ws + 4 * C;
    float* invPatch  = ws + 20 * C;
#pragma unroll
    for (int dy = 0; dy < 4; ++dy) {
        int row = min(max(ya + dy - 1, 0), NTAB - 1);  // edge-pad -> clamp
#pragma unroll
        for (int dx = 0; dx < 4; ++dx) {
            int col = min(max(xa + dx - 1, 0), NTAB - 1);
            float m, s;
            if (row == py && col == px) { m = mean; s = stdv; }
            else {
                m = mean_table[(row * NTAB + col) * C + c];
                s = std_table[(row * NTAB + col) * C + c];
            }
            meanPatch[(dy * 4 + dx) * C + c] = m;
            invPatch[(dy * 4 + dx) * C + c] = 1.0f / s;
        }
    }
}

// ---------------- Stage 3: main map ----------------
// blocks [0,1024): real half. block = (row o, channel-group g of 32).
//   Hoist y-contraction of both patches into LDS (Am/Ai: 4 x 32), then per
//   channel each thread does an x-contraction (8 FMA) + normalize.
// blocks [1024,2048): pre half, elementwise affine with float4.
__global__ __launch_bounds__(256) void main_kernel(const float* __restrict__ x,
                                                   const float* __restrict__ weight,
                                                   const float* __restrict__ bias,
                                                   const float* __restrict__ ws,
                                                   float* __restrict__ out) {
    int b = blockIdx.x;
    if (b < 1024) {
        int o = b & 255;
        int g = b >> 8;
        int p = threadIdx.x;
        float wy[4], wx[4];
        bicubic_w4(o, wy);  // block-uniform
        bicubic_w4(p, wx);  // per-thread
        const float* meanPatch = ws + 4 * C;
        const float* invPatch  = ws + 20 * C;
        __shared__ float Am[4 * 32];
        __shared__ float Ai[4 * 32];
        {
            int t = threadIdx.x;
            int xx = (t & 127) >> 5;
            int cc = t & 31;
            int c = g * 32 + cc;
            const float* src = (t < 128) ? meanPatch : invPatch;
            float a = 0.0f;
#pragma unroll
            for (int y = 0; y < 4; ++y) a += wy[y] * src[(y * 4 + xx) * C + c];
            if (t < 128) Am[xx * 32 + cc] = a;
            else         Ai[xx * 32 + cc] = a;
        }
        __syncthreads();
        const float* xrow = x + o * W + p;
        float* orow = out + o * W + p;
        for (int cc = 0; cc < 32; ++cc) {
            int c = g * 32 + cc;
            float m = 0.0f, iv = 0.0f;
#pragma unroll
            for (int xx = 0; xx < 4; ++xx) {
                m  += wx[xx] * Am[xx * 32 + cc];  // LDS broadcast (uniform addr)
                iv += wx[xx] * Ai[xx * 32 + cc];
            }
            float xv = xrow[(size_t)c * HW];
            orow[(size_t)c * HW] = (xv - m) * iv * weight[c] + bias[c];
        }
    } else {
        int bb = b - 1024;
        const float4* xin = (const float4*)(x + CHW);
        float4* outp = (float4*)(out + CHW);
        const float* scaleP = ws + 2 * C;
        const float* biasP  = ws + 3 * C;
        int i = bb * 256 + threadIdx.x;
#pragma unroll
        for (int k = 0; k < 8; ++k) {
            int j = i + k * 262144;          // CHW/4 = 2,097,152 float4 total
            float4 v = xin[j];
            int c = j >> 14;                 // HW/4 = 16384 float4 per channel
            float sp = scaleP[c], bp = biasP[c];
            float4 r;
            r.x = v.x * sp + bp;
            r.y = v.y * sp + bp;
            r.z = v.z * sp + bp;
            r.w = v.w * sp + bp;
            outp[j] = r;
        }
    }
}

extern "C" void kernel_launch(void* const* d_in, const int* in_sizes, int n_in,
                              void* d_out, int out_size, void* d_ws, size_t ws_size,
                              hipStream_t stream) {
    const float* x          = (const float*)d_in[0];
    const float* mean_table = (const float*)d_in[1];
    const float* std_table  = (const float*)d_in[2];
    const float* weight     = (const float*)d_in[3];
    const float* bias       = (const float*)d_in[4];
    const int* yA  = (const int*)d_in[5];
    const int* xA  = (const int*)d_in[6];
    const int* pyA = (const int*)d_in[7];
    const int* pxA = (const int*)d_in[8];
    float* out = (float*)d_out;
    float* ws  = (float*)d_ws;

    hipMemsetAsync(ws, 0, 2 * C * sizeof(float), stream);  // atomic targets
    stats_kernel<<<C * 8, 256, 0, stream>>>(x, ws);
    finalize_kernel<<<1, 128, 0, stream>>>(mean_table, std_table, weight, bias,
                                           yA, xA, pyA, pxA, ws);
    main_kernel<<<2048, 256, 0, stream>>>(x, weight, bias, ws, out);
}

// Round 2
// 137.745 us; speedup vs baseline: 1.0281x; 1.0281x over previous
//
#include <hip/hip_runtime.h>
#include <hip/hip_bf16.h>

#define C 128
#define H 256
#define W 256
#define HW (H * W)
#define CHW (C * H * W)
#define NTAB 16

// PyTorch bicubic kernel, a = -0.75
__device__ __forceinline__ float cubic075(float u) {
    float au = fabsf(u);
    float near_ = (1.25f * au - 2.25f) * au * au + 1.0f;
    float far_  = -0.75f * (((au - 5.0f) * au + 8.0f) * au - 4.0f);
    return au <= 1.0f ? near_ : (au < 2.0f ? far_ : 0.0f);
}

// Weights for output index o of _bicubic_weight_matrix(768, 4)[128:384]
__device__ __forceinline__ void bicubic_w4(int o, float* w4) {
    const float scale = 4.0f / 768.0f;
    float src = ((float)(o + 128) + 0.5f) * scale - 0.5f;
    float i0f = floorf(src);
    float t = src - i0f;
    int i0 = (int)i0f;
    w4[0] = w4[1] = w4[2] = w4[3] = 0.0f;
#pragma unroll
    for (int j = 0; j < 4; ++j) {
        int off = j - 1;
        float wv = cubic075(t - (float)off);
        int idx = i0 + off;
        idx = idx < 0 ? 0 : (idx > 3 ? 3 : idx);
        w4[idx] += wv;
    }
}

// ---------------- Stage 1: per-channel partial sums over pre_x ----------------
// grid = C*8 blocks of 256 threads; block (c,seg) reduces 8192 elements and
// writes its partial to ws[c*8+seg] (sum) / ws[1024 + c*8+seg] (sumsq).
// Deterministic slots -> no atomics -> no memset dispatch needed.
__global__ __launch_bounds__(256) void stats_kernel(const float* __restrict__ x,
                                                    float* __restrict__ ws) {
    int c = blockIdx.x >> 3;
    int seg = blockIdx.x & 7;
    const float4* x4 = (const float4*)(x + CHW) + (size_t)c * (HW / 4) + seg * 2048;
    float s = 0.0f, s2 = 0.0f;
#pragma unroll
    for (int k = 0; k < 8; ++k) {
        float4 v = x4[k * 256 + threadIdx.x];
        s  += v.x + v.y + v.z + v.w;
        s2 += v.x * v.x + v.y * v.y + v.z * v.z + v.w * v.w;
    }
#pragma unroll
    for (int off = 32; off > 0; off >>= 1) {
        s  += __shfl_down(s, off);
        s2 += __shfl_down(s2, off);
    }
    __shared__ float sd[8];
    int wid = threadIdx.x >> 6;
    if ((threadIdx.x & 63) == 0) { sd[wid] = s; sd[4 + wid] = s2; }
    __syncthreads();
    if (threadIdx.x == 0) {
        ws[c * 8 + seg]        = sd[0] + sd[1] + sd[2] + sd[3];
        ws[1024 + c * 8 + seg] = sd[4] + sd[5] + sd[6] + sd[7];
    }
}

__device__ __forceinline__ void channel_stats(const float* __restrict__ ws, int c,
                                              float& mean, float& stdv) {
    float s = 0.0f, s2 = 0.0f;
#pragma unroll
    for (int k = 0; k < 8; ++k) { s += ws[c * 8 + k]; s2 += ws[1024 + c * 8 + k]; }
    const float n = (float)HW;
    mean = s / n;
    float var = (s2 - s * s / n) / (n - 1.0f);
    stdv = sqrtf(var);
}

// ---------------- Stage 2: fused finalize + map ----------------
// blocks [0,1024): real half. block = (row o, channel-group g of 32).
//   Block preamble rebuilds the 4x4 patch for its 32 channels from the
//   (L2-resident) tables + partial sums, y-contracts into LDS Am/Ai[4][32],
//   then each wave streams one full row per channel with float4 (1KB/wave).
// blocks [1024,2048): pre half. Block preamble builds per-channel affine in
//   LDS, then elementwise float4 map.
__global__ __launch_bounds__(256) void main_kernel(
    const float* __restrict__ x,
    const float* __restrict__ mean_table, const float* __restrict__ std_table,
    const float* __restrict__ weight, const float* __restrict__ bias,
    const int* __restrict__ yA, const int* __restrict__ xA,
    const int* __restrict__ pyA, const int* __restrict__ pxA,
    const float* __restrict__ ws, float* __restrict__ out) {
    int b = blockIdx.x;
    int t = threadIdx.x;
    if (b < 1024) {
        int o = b & 255;
        int g = b >> 8;
        __shared__ float patchM[16 * 32];
        __shared__ float patchI[16 * 32];
        __shared__ float Am[4 * 32], Ai[4 * 32], Wgt[32], Bs[32];
        {
            int cc = t & 31;
            int e0 = t >> 5;  // 0..7
            int c = g * 32 + cc;
            float mean, stdv;
            channel_stats(ws, c, mean, stdv);
            int ya = min(max(*yA, 0), 15);
            int xa = min(max(*xA, 0), 15);
            int py = *pyA, px = *pxA;
#pragma unroll
            for (int e = e0; e < 16; e += 8) {
                int row = min(max(ya + (e >> 2) - 1, 0), NTAB - 1);
                int col = min(max(xa + (e & 3) - 1, 0), NTAB - 1);
                float m, s;
                if (row == py && col == px) { m = mean; s = stdv; }
                else {
                    m = mean_table[(row * NTAB + col) * C + c];
                    s = std_table[(row * NTAB + col) * C + c];
                }
                patchM[e * 32 + cc] = m;
                patchI[e * 32 + cc] = 1.0f / s;
            }
            if (e0 == 0) { Wgt[cc] = weight[c]; Bs[cc] = bias[c]; }
        }
        __syncthreads();
        float wy[4];
        bicubic_w4(o, wy);
        {
            int xx = (t >> 5) & 3;
            int cc = t & 31;
            const float* src = (t < 128) ? patchM : patchI;
            float a = 0.0f;
#pragma unroll
            for (int y = 0; y < 4; ++y) a += wy[y] * src[(y * 4 + xx) * 32 + cc];
            if (t < 128) Am[xx * 32 + cc] = a;
            else         Ai[xx * 32 + cc] = a;
        }
        __syncthreads();

        int w = t >> 6, l = t & 63;
        float wx[4][4];
#pragma unroll
        for (int e = 0; e < 4; ++e) bicubic_w4(4 * l + e, wx[e]);
        const float4* xin = (const float4*)x;
        float4* outp = (float4*)out;
#pragma unroll
        for (int k = 0; k < 8; ++k) {
            int cc = w * 8 + k;                    // channel uniform per wave
            int c = g * 32 + cc;
            size_t base = ((size_t)c * HW + o * W) / 4 + l;
            float4 v = xin[base];
            float wgt = Wgt[cc], bsv = Bs[cc];
            float r[4], vv[4] = {v.x, v.y, v.z, v.w};
#pragma unroll
            for (int e = 0; e < 4; ++e) {
                float m = 0.0f, iv = 0.0f;
#pragma unroll
                for (int xx = 0; xx < 4; ++xx) {
                    m  += wx[e][xx] * Am[xx * 32 + cc];  // LDS broadcast
                    iv += wx[e][xx] * Ai[xx * 32 + cc];
                }
                r[e] = (vv[e] - m) * iv * wgt + bsv;
            }
            float4 ro = {r[0], r[1], r[2], r[3]};
            outp[base] = ro;
        }
    } else {
        int bb = b - 1024;
        __shared__ float Sp[C], Bp[C];
        if (t < C) {
            float mean, stdv;
            channel_stats(ws, t, mean, stdv);
            float sp = weight[t] / stdv;
            Sp[t] = sp;
            Bp[t] = bias[t] - mean * sp;
        }
        __syncthreads();
        const float4* xin = (const float4*)(x + CHW);
        float4* outp = (float4*)(out + CHW);
        int i = bb * 256 + t;
#pragma unroll
        for (int k = 0; k < 8; ++k) {
            int j = i + k * 262144;          // CHW/4 = 2,097,152 float4 total
            float4 v = xin[j];
            int c = j >> 14;                 // HW/4 = 16384 float4 per channel
            float sp = Sp[c], bp = Bp[c];    // uniform per wave -> broadcast
            float4 r;
            r.x = v.x * sp + bp;
            r.y = v.y * sp + bp;
            r.z = v.z * sp + bp;
            r.w = v.w * sp + bp;
            outp[j] = r;
        }
    }
}

extern "C" void kernel_launch(void* const* d_in, const int* in_sizes, int n_in,
                              void* d_out, int out_size, void* d_ws, size_t ws_size,
                              hipStream_t stream) {
    const float* x          = (const float*)d_in[0];
    const float* mean_table = (const float*)d_in[1];
    const float* std_table  = (const float*)d_in[2];
    const float* weight     = (const float*)d_in[3];
    const float* bias       = (const float*)d_in[4];
    const int* yA  = (const int*)d_in[5];
    const int* xA  = (const int*)d_in[6];
    const int* pyA = (const int*)d_in[7];
    const int* pxA = (const int*)d_in[8];
    float* out = (float*)d_out;
    float* ws  = (float*)d_ws;

    stats_kernel<<<C * 8, 256, 0, stream>>>(x, ws);
    main_kernel<<<2048, 256, 0, stream>>>(x, mean_table, std_table, weight, bias,
                                          yA, xA, pyA, pxA, ws, out);
}